// Round 1
// baseline (600.783 us; speedup 1.0000x reference)
//
#include <hip/hip_runtime.h>
#include <hip/hip_bf16.h>

// EPMoE: E=8 experts, K=2 top-k, D=1024, F=2048, T=2048 tokens, ROWS=T*K=4096.
// Pipeline: route (stable counting sort + tile schedule) -> gemm1 (x @ wi0/wi1,
// fused SwiGLU -> h bf16 in ws) -> gemm2 (h @ wo, atomicAdd-combine into out).
// All MFMA in bf16 (threshold 3.7e-2 = 8*bf16eps*|out| licenses this).
// ws usage: tile_meta 1KB + sorted_flat 16KB + h 16MB  (~16.8MB total).

#define D_DIM 1024
#define F_DIM 2048
#define ROWS 4096
#define BK 64
#define LDK 72          // padded LDS k-stride (elems); 144B rows -> 16B-aligned b128
#define MAXTILE 40

using f32x4 = __attribute__((ext_vector_type(4))) float;
using s16x8 = __attribute__((ext_vector_type(8))) short;

__device__ __forceinline__ unsigned pack_trunc(float lo, float hi) {
  // two fp32 -> packed bf16x2 (RTZ; error budget analyzed: final |err| << 3.7e-2)
  return (__float_as_uint(lo) >> 16) | (__float_as_uint(hi) & 0xffff0000u);
}
__device__ __forceinline__ unsigned short bf_rn(float f) {
  unsigned u = __float_as_uint(f);
  u += 0x7fffu + ((u >> 16) & 1u);
  return (unsigned short)(u >> 16);
}

// ---------------- routing: stable counting sort by expert ----------------
__global__ __launch_bounds__(512) void route_kernel(const int* __restrict__ ids,
                                                    int* __restrict__ sorted_flat,
                                                    int* __restrict__ tile_meta) {
  __shared__ int cnt[8];
  __shared__ int off[9];
  const int tid = threadIdx.x;
  const int w = tid >> 6, lane = tid & 63;
  int c = 0;
  for (int base = 0; base < ROWS; base += 64) {
    int e = ids[base + lane];
    c += __popcll(__ballot(e == w));
  }
  if (lane == 0) cnt[w] = c;
  __syncthreads();
  if (tid == 0) {
    int o = 0;
    for (int e = 0; e < 8; e++) { off[e] = o; o += cnt[e]; }
    off[8] = o;
    int nT = 0;
    for (int e = 0; e < 8; e++) {
      for (int r0 = off[e]; r0 < off[e + 1]; r0 += 128) {
        tile_meta[1 + 3 * nT] = r0;          // tile row start (global sorted row)
        tile_meta[2 + 3 * nT] = off[e + 1];  // expert segment end (store mask)
        tile_meta[3 + 3 * nT] = e;           // expert id
        nT++;
      }
    }
    tile_meta[0] = nT;                       // <= 40 guaranteed
  }
  __syncthreads();
  int pos = off[w];
  const unsigned long long below = (1ull << lane) - 1ull;
  for (int base = 0; base < ROWS; base += 64) {
    int e = ids[base + lane];
    unsigned long long m = __ballot(e == w);
    if (e == w) sorted_flat[pos + __popcll(m & below)] = base + lane;
    pos += __popcll(m);
  }
}

__global__ void zero_kernel(float4* __restrict__ p, int n4) {
  int i = blockIdx.x * blockDim.x + threadIdx.x;
  if (i < n4) p[i] = float4{0.f, 0.f, 0.f, 0.f};
}

// stage a 64(k) x 128(n) fp32 tile of W (row stride ldw, base already at k0,n0)
// transposed+converted into Bs[n][k] bf16, LDK-padded. k-pair packed b32 writes,
// ~4-way bank conflicts (16nq+4c+kp pattern). Global: 8 rows x 128B per instr.
__device__ __forceinline__ void stage_bt(const float* __restrict__ Wt, int ldw,
                                         unsigned short* Bs, int tid) {
#pragma unroll
  for (int it = 0; it < 4; it++) {
    const int kp = (tid & 7) + it * 8;   // k-pair index, k = 2*kp
    const int nq = tid >> 3;             // n-quad 0..31
    const float* p = Wt + (size_t)(2 * kp) * ldw + nq * 4;
    const float4 va = *(const float4*)p;
    const float4 vb = *(const float4*)(p + ldw);
    unsigned short* b = Bs + (nq * 4) * LDK + 2 * kp;
    *(unsigned*)(b)           = pack_trunc(va.x, vb.x);
    *(unsigned*)(b + LDK)     = pack_trunc(va.y, vb.y);
    *(unsigned*)(b + 2 * LDK) = pack_trunc(va.z, vb.z);
    *(unsigned*)(b + 3 * LDK) = pack_trunc(va.w, vb.w);
  }
}

// ---------------- GEMM1: x_sorted @ (wi0, wi1) -> h = silu(g0)*g1 ----------------
__global__ __launch_bounds__(256, 2) void gemm1_kernel(
    const float* __restrict__ x, const float* __restrict__ wi0,
    const float* __restrict__ wi1, const int* __restrict__ sorted_flat,
    const int* __restrict__ tile_meta, unsigned short* __restrict__ h) {
  __shared__ unsigned short As[128 * LDK];
  __shared__ unsigned short B0s[128 * LDK];
  __shared__ unsigned short B1s[128 * LDK];
  __shared__ int tok[128];

  const int nT = tile_meta[0];
  const int tile = blockIdx.x;
  if (tile >= nT) return;
  const int row0 = tile_meta[1 + 3 * tile];
  const int rowEnd = tile_meta[2 + 3 * tile];
  const int e = tile_meta[3 + 3 * tile];
  const int n0 = blockIdx.y * 128;
  const float* W0 = wi0 + (size_t)e * D_DIM * F_DIM;
  const float* W1 = wi1 + (size_t)e * D_DIM * F_DIM;

  const int tid = threadIdx.x;
  if (tid < 128) {
    int r = row0 + tid; if (r > ROWS - 1) r = ROWS - 1;
    tok[tid] = sorted_flat[r] >> 1;   // TOPK=2: flat -> token
  }

  f32x4 acc0[4][4], acc1[4][4];
#pragma unroll
  for (int i = 0; i < 4; i++)
#pragma unroll
    for (int j = 0; j < 4; j++) { acc0[i][j] = 0.f; acc1[i][j] = 0.f; }

  const int lane = tid & 63, wv = tid >> 6;
  const int wm = (wv & 1) * 64, wn = (wv >> 1) * 64;
  const int lm = lane & 15, lq = lane >> 4;

  for (int k0 = 0; k0 < D_DIM; k0 += BK) {
    __syncthreads();  // prev-iter frag reads done (also orders tok[] on iter 0)
    // ---- stage A: gather x rows, fp32 -> bf16, k-contiguous ----
#pragma unroll
    for (int i = 0; i < 8; i++) {
      int idx = tid + i * 256;
      int m = idx >> 4, kq = idx & 15;
      float4 v = *(const float4*)(x + (size_t)tok[m] * D_DIM + k0 + kq * 4);
      *(uint2*)&As[m * LDK + kq * 4] =
          make_uint2(pack_trunc(v.x, v.y), pack_trunc(v.z, v.w));
    }
    stage_bt(W0 + (size_t)k0 * F_DIM + n0, F_DIM, B0s, tid);
    stage_bt(W1 + (size_t)k0 * F_DIM + n0, F_DIM, B1s, tid);
    __syncthreads();
#pragma unroll
    for (int ks = 0; ks < BK; ks += 32) {
      s16x8 af[4], b0[4], b1[4];
#pragma unroll
      for (int t = 0; t < 4; t++) {
        af[t] = *(const s16x8*)&As[(wm + t * 16 + lm) * LDK + ks + lq * 8];
        b0[t] = *(const s16x8*)&B0s[(wn + t * 16 + lm) * LDK + ks + lq * 8];
        b1[t] = *(const s16x8*)&B1s[(wn + t * 16 + lm) * LDK + ks + lq * 8];
      }
#pragma unroll
      for (int im = 0; im < 4; im++)
#pragma unroll
        for (int in = 0; in < 4; in++) {
          acc0[im][in] = __builtin_amdgcn_mfma_f32_16x16x32_bf16(
              af[im], b0[in], acc0[im][in], 0, 0, 0);
          acc1[im][in] = __builtin_amdgcn_mfma_f32_16x16x32_bf16(
              af[im], b1[in], acc1[im][in], 0, 0, 0);
        }
    }
  }
  // ---- epilogue: h = silu(g0) * g1, bf16 store (C/D: col=lane&15,row=lq*4+r) ----
#pragma unroll
  for (int im = 0; im < 4; im++) {
    int gmB = row0 + wm + im * 16 + lq * 4;
#pragma unroll
    for (int in = 0; in < 4; in++) {
      int gn = n0 + wn + in * 16 + lm;
#pragma unroll
      for (int r = 0; r < 4; r++) {
        int gm = gmB + r;
        if (gm < rowEnd) {
          float g = acc0[im][in][r];
          float s = g / (1.f + __expf(-g));
          h[(size_t)gm * F_DIM + gn] = bf_rn(s * acc1[im][in][r]);
        }
      }
    }
  }
}

// ---------------- GEMM2: h @ wo, weighted atomicAdd combine into out ----------------
__global__ __launch_bounds__(256, 3) void gemm2_kernel(
    const unsigned short* __restrict__ h, const float* __restrict__ wo,
    const float* __restrict__ tw, const int* __restrict__ sorted_flat,
    const int* __restrict__ tile_meta, float* __restrict__ out) {
  __shared__ unsigned short As[128 * LDK];
  __shared__ unsigned short Bs[128 * LDK];
  __shared__ int sTok[128];
  __shared__ float sWgt[128];

  const int nT = tile_meta[0];
  const int tile = blockIdx.x;
  if (tile >= nT) return;
  const int row0 = tile_meta[1 + 3 * tile];
  const int rowEnd = tile_meta[2 + 3 * tile];
  const int e = tile_meta[3 + 3 * tile];
  const int n0 = blockIdx.y * 128;
  const float* W = wo + (size_t)e * F_DIM * D_DIM;

  const int tid = threadIdx.x;
  if (tid < 128) {
    int r = row0 + tid; if (r > ROWS - 1) r = ROWS - 1;
    int fl = sorted_flat[r];
    sTok[tid] = fl >> 1;
    sWgt[tid] = tw[fl];
  }

  f32x4 acc[4][4];
#pragma unroll
  for (int i = 0; i < 4; i++)
#pragma unroll
    for (int j = 0; j < 4; j++) acc[i][j] = 0.f;

  const int lane = tid & 63, wv = tid >> 6;
  const int wm = (wv & 1) * 64, wn = (wv >> 1) * 64;
  const int lm = lane & 15, lq = lane >> 4;

  for (int k0 = 0; k0 < F_DIM; k0 += BK) {
    __syncthreads();
    // ---- stage A: h rows (already bf16, k-contiguous) ----
#pragma unroll
    for (int i = 0; i < 8; i++) {
      int idx = tid + i * 256;
      int m = idx >> 4, kq = idx & 15;
      int gm = row0 + m; if (gm > ROWS - 1) gm = ROWS - 1;
      *(uint2*)&As[m * LDK + kq * 4] =
          *(const uint2*)(h + (size_t)gm * F_DIM + k0 + kq * 4);
    }
    stage_bt(W + (size_t)k0 * D_DIM + n0, D_DIM, Bs, tid);
    __syncthreads();
#pragma unroll
    for (int ks = 0; ks < BK; ks += 32) {
      s16x8 af[4], bf[4];
#pragma unroll
      for (int t = 0; t < 4; t++) {
        af[t] = *(const s16x8*)&As[(wm + t * 16 + lm) * LDK + ks + lq * 8];
        bf[t] = *(const s16x8*)&Bs[(wn + t * 16 + lm) * LDK + ks + lq * 8];
      }
#pragma unroll
      for (int im = 0; im < 4; im++)
#pragma unroll
        for (int in = 0; in < 4; in++)
          acc[im][in] = __builtin_amdgcn_mfma_f32_16x16x32_bf16(
              af[im], bf[in], acc[im][in], 0, 0, 0);
    }
  }
#pragma unroll
  for (int im = 0; im < 4; im++) {
    int lrB = wm + im * 16 + lq * 4;
#pragma unroll
    for (int in = 0; in < 4; in++) {
      int gn = n0 + wn + in * 16 + lm;
#pragma unroll
      for (int r = 0; r < 4; r++) {
        int lr = lrB + r;
        int gm = row0 + lr;
        if (gm < rowEnd)
          atomicAdd(out + (size_t)sTok[lr] * D_DIM + gn, sWgt[lr] * acc[im][in][r]);
      }
    }
  }
}

extern "C" void kernel_launch(void* const* d_in, const int* in_sizes, int n_in,
                              void* d_out, int out_size, void* d_ws, size_t ws_size,
                              hipStream_t stream) {
  const float* x   = (const float*)d_in[0];   // hidden_states [2048,1024]
  const float* tw  = (const float*)d_in[1];   // topk_weights  [2048,2]
  const int*   ids = (const int*)d_in[2];     // topk_ids      [2048,2]
  const float* wi0 = (const float*)d_in[3];   // [8,1024,2048]
  const float* wi1 = (const float*)d_in[4];   // [8,1024,2048]
  const float* wo  = (const float*)d_in[5];   // [8,2048,1024]
  float* out = (float*)d_out;

  int* tile_meta = (int*)d_ws;                               // 121 ints used
  int* sorted_flat = tile_meta + 256;                        // 4096 ints
  unsigned short* h = (unsigned short*)((char*)d_ws + 32768);// 4096*2048 bf16

  route_kernel<<<1, 512, 0, stream>>>(ids, sorted_flat, tile_meta);
  zero_kernel<<<(out_size / 4 + 255) / 256, 256, 0, stream>>>((float4*)out,
                                                              out_size / 4);
  dim3 g1(MAXTILE, F_DIM / 128);   // 40 x 16
  gemm1_kernel<<<g1, 256, 0, stream>>>(x, wi0, wi1, sorted_flat, tile_meta, h);
  dim3 g2(MAXTILE, D_DIM / 128);   // 40 x 8
  gemm2_kernel<<<g2, 256, 0, stream>>>(h, wo, tw, sorted_flat, tile_meta, out);
}

// Round 2
// 372.995 us; speedup vs baseline: 1.6107x; 1.6107x over previous
//
#include <hip/hip_runtime.h>
#include <hip/hip_bf16.h>

// EPMoE: E=8, K=2, D=1024, F=2048, T=2048, ROWS=4096.
// Fast path (needs ~120MB ws): route -> convT (fp32 W -> bf16 W^T) -> gather
// (x -> x_sorted bf16) -> gemm1 (m97-style global_load_lds staging, SwiGLU) ->
// gemm2 (atomicAdd combine). Fallback (small ws): round-0 fused-convert kernels.

#define D_DIM 1024
#define F_DIM 2048
#define ROWS 4096
#define MAXTILE 40
#define LDK 72   // fallback-path LDS k-stride

using f32x4 = __attribute__((ext_vector_type(4))) float;
using s16x8 = __attribute__((ext_vector_type(8))) short;

__device__ __forceinline__ unsigned pack_trunc(float lo, float hi) {
  return (__float_as_uint(lo) >> 16) | (__float_as_uint(hi) & 0xffff0000u);
}
__device__ __forceinline__ unsigned short bf_rn(float f) {
  unsigned u = __float_as_uint(f);
  u += 0x7fffu + ((u >> 16) & 1u);
  return (unsigned short)(u >> 16);
}

typedef const __attribute__((address_space(1))) void* gp_t;
typedef __attribute__((address_space(3))) void* lp_t;
__device__ __forceinline__ void load16(const void* g, void* l) {
  // 64 lanes x 16B -> LDS wave-uniform base + lane*16 (pass uniform l!)
  __builtin_amdgcn_global_load_lds((gp_t)g, (lp_t)l, 16, 0, 0);
}

// ---------------- routing: stable counting sort by expert ----------------
__global__ __launch_bounds__(512) void route_kernel(const int* __restrict__ ids,
                                                    int* __restrict__ sorted_flat,
                                                    int* __restrict__ tile_meta) {
  __shared__ int cnt[8];
  __shared__ int off[9];
  const int tid = threadIdx.x;
  const int w = tid >> 6, lane = tid & 63;
  int c = 0;
  for (int base = 0; base < ROWS; base += 64) {
    int e = ids[base + lane];
    c += __popcll(__ballot(e == w));
  }
  if (lane == 0) cnt[w] = c;
  __syncthreads();
  if (tid == 0) {
    int o = 0;
    for (int e = 0; e < 8; e++) { off[e] = o; o += cnt[e]; }
    off[8] = o;
    int nT = 0;
    for (int e = 0; e < 8; e++) {
      for (int r0 = off[e]; r0 < off[e + 1]; r0 += 128) {
        tile_meta[1 + 3 * nT] = r0;
        tile_meta[2 + 3 * nT] = off[e + 1];
        tile_meta[3 + 3 * nT] = e;
        nT++;
      }
    }
    tile_meta[0] = nT;
  }
  __syncthreads();
  int pos = off[w];
  const unsigned long long below = (1ull << lane) - 1ull;
  for (int base = 0; base < ROWS; base += 64) {
    int e = ids[base + lane];
    unsigned long long m = __ballot(e == w);
    if (e == w) sorted_flat[pos + __popcll(m & below)] = base + lane;
    pos += __popcll(m);
  }
}

__global__ void zero_kernel(float4* __restrict__ p, int n4) {
  int i = blockIdx.x * blockDim.x + threadIdx.x;
  if (i < n4) p[i] = float4{0.f, 0.f, 0.f, 0.f};
}

// ---------------- convT: W fp32 [E][Kd][Nd] -> bf16 [E][Nd][Kd] ----------------
__global__ __launch_bounds__(256) void convT_kernel(const float* __restrict__ src,
                                                    unsigned short* __restrict__ dst,
                                                    int Kd, int Nd) {
  __shared__ unsigned short t[64 * 66];  // 66: bank-conflict-free scatter writes
  const int e = blockIdx.z;
  const float* S = src + (size_t)e * Kd * Nd;
  unsigned short* Dp = dst + (size_t)e * Kd * Nd;
  const int n0 = blockIdx.x * 64, k0 = blockIdx.y * 64;
  const int tid = threadIdx.x;
  const int r_ = tid >> 4, c0 = (tid & 15) * 4;
#pragma unroll
  for (int i = 0; i < 4; i++) {
    int r = r_ + i * 16;
    float4 v = *(const float4*)(S + (size_t)(k0 + r) * Nd + n0 + c0);
    t[(c0 + 0) * 66 + r] = bf_rn(v.x);
    t[(c0 + 1) * 66 + r] = bf_rn(v.y);
    t[(c0 + 2) * 66 + r] = bf_rn(v.z);
    t[(c0 + 3) * 66 + r] = bf_rn(v.w);
  }
  __syncthreads();
  const int kb = (tid & 7) * 8;
#pragma unroll
  for (int it = 0; it < 2; it++) {
    int n = (tid >> 3) + it * 32;
    const unsigned* p = (const unsigned*)&t[n * 66 + kb];
    uint4 o = make_uint4(p[0], p[1], p[2], p[3]);
    *(uint4*)(Dp + (size_t)(n0 + n) * Kd + k0 + kb) = o;
  }
}

// ---------------- gather: x fp32 -> x_sorted bf16 (one row per block) ----------
__global__ __launch_bounds__(256) void gather_kernel(const float* __restrict__ x,
                                                     const int* __restrict__ sorted_flat,
                                                     unsigned short* __restrict__ xs) {
  const int r = blockIdx.x;
  const int tok = sorted_flat[r] >> 1;
  const float4 v = *(const float4*)(x + (size_t)tok * D_DIM + threadIdx.x * 4);
  *(uint2*)(xs + (size_t)r * D_DIM + threadIdx.x * 4) =
      make_uint2((unsigned)bf_rn(v.x) | ((unsigned)bf_rn(v.y) << 16),
                 (unsigned)bf_rn(v.z) | ((unsigned)bf_rn(v.w) << 16));
}

// ---------------- GEMM1 fast: xs @ (w0T,w1T) -> h = silu(g0)*g1 ----------------
__global__ __launch_bounds__(256, 2) void gemm1_kernel(
    const unsigned short* __restrict__ xs, const unsigned short* __restrict__ w0T,
    const unsigned short* __restrict__ w1T, const int* __restrict__ tile_meta,
    unsigned short* __restrict__ h) {
  __shared__ unsigned short As[128 * 64];
  __shared__ unsigned short B0s[128 * 64];
  __shared__ unsigned short B1s[128 * 64];
  const int tile = blockIdx.x;
  if (tile >= tile_meta[0]) return;
  const int row0 = tile_meta[1 + 3 * tile];
  const int rowEnd = tile_meta[2 + 3 * tile];
  const int e = tile_meta[3 + 3 * tile];
  const int n0 = blockIdx.y * 128;
  const unsigned short* W0 = w0T + ((size_t)e * F_DIM + n0) * D_DIM;
  const unsigned short* W1 = w1T + ((size_t)e * F_DIM + n0) * D_DIM;

  const int tid = threadIdx.x;
  const int lane = tid & 63, wv = tid >> 6;
  const int wm = (wv & 1) * 64, wn = (wv >> 1) * 64;
  const int lm = lane & 15, lq = lane >> 4;

  f32x4 acc0[4][4], acc1[4][4];
#pragma unroll
  for (int i = 0; i < 4; i++)
#pragma unroll
    for (int j = 0; j < 4; j++) { acc0[i][j] = 0.f; acc1[i][j] = 0.f; }

  for (int k0 = 0; k0 < D_DIM; k0 += 64) {
    __syncthreads();
#pragma unroll
    for (int r = 0; r < 4; r++) {
      const int c = r * 4 + wv;            // 1KB chunk id, wave-uniform
      const int idx = c * 512 + lane * 8;  // elem idx in [128][64] tile
      const int m = idx >> 6, kk = idx & 63;
      int mc = row0 + m; if (mc > ROWS - 1) mc = ROWS - 1;
      load16(xs + (size_t)mc * D_DIM + k0 + kk, (char*)As + c * 1024);
      load16(W0 + (size_t)m * D_DIM + k0 + kk, (char*)B0s + c * 1024);
      load16(W1 + (size_t)m * D_DIM + k0 + kk, (char*)B1s + c * 1024);
    }
    __syncthreads();
#pragma unroll
    for (int ks = 0; ks < 64; ks += 32) {
      s16x8 af[4], b0[4], b1[4];
#pragma unroll
      for (int t = 0; t < 4; t++) {
        af[t] = *(const s16x8*)&As[(wm + t * 16 + lm) * 64 + ks + lq * 8];
        b0[t] = *(const s16x8*)&B0s[(wn + t * 16 + lm) * 64 + ks + lq * 8];
        b1[t] = *(const s16x8*)&B1s[(wn + t * 16 + lm) * 64 + ks + lq * 8];
      }
#pragma unroll
      for (int im = 0; im < 4; im++)
#pragma unroll
        for (int in = 0; in < 4; in++) {
          acc0[im][in] = __builtin_amdgcn_mfma_f32_16x16x32_bf16(
              af[im], b0[in], acc0[im][in], 0, 0, 0);
          acc1[im][in] = __builtin_amdgcn_mfma_f32_16x16x32_bf16(
              af[im], b1[in], acc1[im][in], 0, 0, 0);
        }
    }
  }
#pragma unroll
  for (int im = 0; im < 4; im++) {
    int gmB = row0 + wm + im * 16 + lq * 4;
#pragma unroll
    for (int in = 0; in < 4; in++) {
      int gn = n0 + wn + in * 16 + lm;
#pragma unroll
      for (int r = 0; r < 4; r++) {
        int gm = gmB + r;
        if (gm < rowEnd) {
          float g = acc0[im][in][r];
          float s = g / (1.f + __expf(-g));
          h[(size_t)gm * F_DIM + gn] = bf_rn(s * acc1[im][in][r]);
        }
      }
    }
  }
}

// ---------------- GEMM2 fast: h @ woT, atomicAdd combine ----------------
__global__ __launch_bounds__(256, 3) void gemm2_kernel(
    const unsigned short* __restrict__ h, const unsigned short* __restrict__ woT,
    const float* __restrict__ tw, const int* __restrict__ sorted_flat,
    const int* __restrict__ tile_meta, float* __restrict__ out) {
  __shared__ unsigned short As[128 * 64];
  __shared__ unsigned short Bs[128 * 64];
  __shared__ int sTok[128];
  __shared__ float sWgt[128];
  const int tile = blockIdx.x;
  if (tile >= tile_meta[0]) return;
  const int row0 = tile_meta[1 + 3 * tile];
  const int rowEnd = tile_meta[2 + 3 * tile];
  const int e = tile_meta[3 + 3 * tile];
  const int n0 = blockIdx.y * 128;
  const unsigned short* W = woT + ((size_t)e * D_DIM + n0) * F_DIM;

  const int tid = threadIdx.x;
  if (tid < 128) {
    int r = row0 + tid; if (r > ROWS - 1) r = ROWS - 1;
    int fl = sorted_flat[r];
    sTok[tid] = fl >> 1;
    sWgt[tid] = tw[fl];
  }

  const int lane = tid & 63, wv = tid >> 6;
  const int wm = (wv & 1) * 64, wn = (wv >> 1) * 64;
  const int lm = lane & 15, lq = lane >> 4;

  f32x4 acc[4][4];
#pragma unroll
  for (int i = 0; i < 4; i++)
#pragma unroll
    for (int j = 0; j < 4; j++) acc[i][j] = 0.f;

  for (int k0 = 0; k0 < F_DIM; k0 += 64) {
    __syncthreads();
#pragma unroll
    for (int r = 0; r < 4; r++) {
      const int c = r * 4 + wv;
      const int idx = c * 512 + lane * 8;
      const int m = idx >> 6, kk = idx & 63;
      int mc = row0 + m; if (mc > ROWS - 1) mc = ROWS - 1;
      load16(h + (size_t)mc * F_DIM + k0 + kk, (char*)As + c * 1024);
      load16(W + (size_t)m * F_DIM + k0 + kk, (char*)Bs + c * 1024);
    }
    __syncthreads();
#pragma unroll
    for (int ks = 0; ks < 64; ks += 32) {
      s16x8 af[4], bf[4];
#pragma unroll
      for (int t = 0; t < 4; t++) {
        af[t] = *(const s16x8*)&As[(wm + t * 16 + lm) * 64 + ks + lq * 8];
        bf[t] = *(const s16x8*)&Bs[(wn + t * 16 + lm) * 64 + ks + lq * 8];
      }
#pragma unroll
      for (int im = 0; im < 4; im++)
#pragma unroll
        for (int in = 0; in < 4; in++)
          acc[im][in] = __builtin_amdgcn_mfma_f32_16x16x32_bf16(
              af[im], bf[in], acc[im][in], 0, 0, 0);
    }
  }
#pragma unroll
  for (int im = 0; im < 4; im++) {
    int lrB = wm + im * 16 + lq * 4;
#pragma unroll
    for (int in = 0; in < 4; in++) {
      int gn = n0 + wn + in * 16 + lm;
#pragma unroll
      for (int r = 0; r < 4; r++) {
        int lr = lrB + r;
        int gm = row0 + lr;
        if (gm < rowEnd)
          atomicAdd(out + (size_t)sTok[lr] * D_DIM + gn, sWgt[lr] * acc[im][in][r]);
      }
    }
  }
}

// ================= fallback (round-0) kernels, small-ws path =================
__device__ __forceinline__ void stage_bt(const float* __restrict__ Wt, int ldw,
                                         unsigned short* Bs, int tid) {
#pragma unroll
  for (int it = 0; it < 4; it++) {
    const int kp = (tid & 7) + it * 8;
    const int nq = tid >> 3;
    const float* p = Wt + (size_t)(2 * kp) * ldw + nq * 4;
    const float4 va = *(const float4*)p;
    const float4 vb = *(const float4*)(p + ldw);
    unsigned short* b = Bs + (nq * 4) * LDK + 2 * kp;
    *(unsigned*)(b)           = pack_trunc(va.x, vb.x);
    *(unsigned*)(b + LDK)     = pack_trunc(va.y, vb.y);
    *(unsigned*)(b + 2 * LDK) = pack_trunc(va.z, vb.z);
    *(unsigned*)(b + 3 * LDK) = pack_trunc(va.w, vb.w);
  }
}

__global__ __launch_bounds__(256, 2) void gemm1_fb(
    const float* __restrict__ x, const float* __restrict__ wi0,
    const float* __restrict__ wi1, const int* __restrict__ sorted_flat,
    const int* __restrict__ tile_meta, unsigned short* __restrict__ h) {
  __shared__ unsigned short As[128 * LDK];
  __shared__ unsigned short B0s[128 * LDK];
  __shared__ unsigned short B1s[128 * LDK];
  __shared__ int tok[128];
  const int tile = blockIdx.x;
  if (tile >= tile_meta[0]) return;
  const int row0 = tile_meta[1 + 3 * tile];
  const int rowEnd = tile_meta[2 + 3 * tile];
  const int e = tile_meta[3 + 3 * tile];
  const int n0 = blockIdx.y * 128;
  const float* W0 = wi0 + (size_t)e * D_DIM * F_DIM;
  const float* W1 = wi1 + (size_t)e * D_DIM * F_DIM;
  const int tid = threadIdx.x;
  if (tid < 128) {
    int r = row0 + tid; if (r > ROWS - 1) r = ROWS - 1;
    tok[tid] = sorted_flat[r] >> 1;
  }
  f32x4 acc0[4][4], acc1[4][4];
#pragma unroll
  for (int i = 0; i < 4; i++)
#pragma unroll
    for (int j = 0; j < 4; j++) { acc0[i][j] = 0.f; acc1[i][j] = 0.f; }
  const int lane = tid & 63, wv = tid >> 6;
  const int wm = (wv & 1) * 64, wn = (wv >> 1) * 64;
  const int lm = lane & 15, lq = lane >> 4;
  for (int k0 = 0; k0 < D_DIM; k0 += 64) {
    __syncthreads();
#pragma unroll
    for (int i = 0; i < 8; i++) {
      int idx = tid + i * 256;
      int m = idx >> 4, kq = idx & 15;
      float4 v = *(const float4*)(x + (size_t)tok[m] * D_DIM + k0 + kq * 4);
      *(uint2*)&As[m * LDK + kq * 4] =
          make_uint2(pack_trunc(v.x, v.y), pack_trunc(v.z, v.w));
    }
    stage_bt(W0 + (size_t)k0 * F_DIM + n0, F_DIM, B0s, tid);
    stage_bt(W1 + (size_t)k0 * F_DIM + n0, F_DIM, B1s, tid);
    __syncthreads();
#pragma unroll
    for (int ks = 0; ks < 64; ks += 32) {
      s16x8 af[4], b0[4], b1[4];
#pragma unroll
      for (int t = 0; t < 4; t++) {
        af[t] = *(const s16x8*)&As[(wm + t * 16 + lm) * LDK + ks + lq * 8];
        b0[t] = *(const s16x8*)&B0s[(wn + t * 16 + lm) * LDK + ks + lq * 8];
        b1[t] = *(const s16x8*)&B1s[(wn + t * 16 + lm) * LDK + ks + lq * 8];
      }
#pragma unroll
      for (int im = 0; im < 4; im++)
#pragma unroll
        for (int in = 0; in < 4; in++) {
          acc0[im][in] = __builtin_amdgcn_mfma_f32_16x16x32_bf16(
              af[im], b0[in], acc0[im][in], 0, 0, 0);
          acc1[im][in] = __builtin_amdgcn_mfma_f32_16x16x32_bf16(
              af[im], b1[in], acc1[im][in], 0, 0, 0);
        }
    }
  }
#pragma unroll
  for (int im = 0; im < 4; im++) {
    int gmB = row0 + wm + im * 16 + lq * 4;
#pragma unroll
    for (int in = 0; in < 4; in++) {
      int gn = n0 + wn + in * 16 + lm;
#pragma unroll
      for (int r = 0; r < 4; r++) {
        int gm = gmB + r;
        if (gm < rowEnd) {
          float g = acc0[im][in][r];
          float s = g / (1.f + __expf(-g));
          h[(size_t)gm * F_DIM + gn] = bf_rn(s * acc1[im][in][r]);
        }
      }
    }
  }
}

__global__ __launch_bounds__(256, 3) void gemm2_fb(
    const unsigned short* __restrict__ h, const float* __restrict__ wo,
    const float* __restrict__ tw, const int* __restrict__ sorted_flat,
    const int* __restrict__ tile_meta, float* __restrict__ out) {
  __shared__ unsigned short As[128 * LDK];
  __shared__ unsigned short Bs[128 * LDK];
  __shared__ int sTok[128];
  __shared__ float sWgt[128];
  const int tile = blockIdx.x;
  if (tile >= tile_meta[0]) return;
  const int row0 = tile_meta[1 + 3 * tile];
  const int rowEnd = tile_meta[2 + 3 * tile];
  const int e = tile_meta[3 + 3 * tile];
  const int n0 = blockIdx.y * 128;
  const float* W = wo + (size_t)e * F_DIM * D_DIM;
  const int tid = threadIdx.x;
  if (tid < 128) {
    int r = row0 + tid; if (r > ROWS - 1) r = ROWS - 1;
    int fl = sorted_flat[r];
    sTok[tid] = fl >> 1;
    sWgt[tid] = tw[fl];
  }
  f32x4 acc[4][4];
#pragma unroll
  for (int i = 0; i < 4; i++)
#pragma unroll
    for (int j = 0; j < 4; j++) acc[i][j] = 0.f;
  const int lane = tid & 63, wv = tid >> 6;
  const int wm = (wv & 1) * 64, wn = (wv >> 1) * 64;
  const int lm = lane & 15, lq = lane >> 4;
  for (int k0 = 0; k0 < F_DIM; k0 += 64) {
    __syncthreads();
#pragma unroll
    for (int i = 0; i < 8; i++) {
      int idx = tid + i * 256;
      int m = idx >> 4, kq = idx & 15;
      int gm = row0 + m; if (gm > ROWS - 1) gm = ROWS - 1;
      *(uint2*)&As[m * LDK + kq * 4] =
          *(const uint2*)(h + (size_t)gm * F_DIM + k0 + kq * 4);
    }
    stage_bt(W + (size_t)k0 * D_DIM + n0, D_DIM, Bs, tid);
    __syncthreads();
#pragma unroll
    for (int ks = 0; ks < 64; ks += 32) {
      s16x8 af[4], bf[4];
#pragma unroll
      for (int t = 0; t < 4; t++) {
        af[t] = *(const s16x8*)&As[(wm + t * 16 + lm) * LDK + ks + lq * 8];
        bf[t] = *(const s16x8*)&Bs[(wn + t * 16 + lm) * LDK + ks + lq * 8];
      }
#pragma unroll
      for (int im = 0; im < 4; im++)
#pragma unroll
        for (int in = 0; in < 4; in++)
          acc[im][in] = __builtin_amdgcn_mfma_f32_16x16x32_bf16(
              af[im], bf[in], acc[im][in], 0, 0, 0);
    }
  }
#pragma unroll
  for (int im = 0; im < 4; im++) {
    int lrB = wm + im * 16 + lq * 4;
#pragma unroll
    for (int in = 0; in < 4; in++) {
      int gn = n0 + wn + in * 16 + lm;
#pragma unroll
      for (int r = 0; r < 4; r++) {
        int lr = lrB + r;
        int gm = row0 + lr;
        if (gm < rowEnd)
          atomicAdd(out + (size_t)sTok[lr] * D_DIM + gn, sWgt[lr] * acc[im][in][r]);
      }
    }
  }
}

extern "C" void kernel_launch(void* const* d_in, const int* in_sizes, int n_in,
                              void* d_out, int out_size, void* d_ws, size_t ws_size,
                              hipStream_t stream) {
  const float* x   = (const float*)d_in[0];
  const float* tw  = (const float*)d_in[1];
  const int*   ids = (const int*)d_in[2];
  const float* wi0 = (const float*)d_in[3];
  const float* wi1 = (const float*)d_in[4];
  const float* wo  = (const float*)d_in[5];
  float* out = (float*)d_out;

  int* tile_meta = (int*)d_ws;
  int* sorted_flat = tile_meta + 256;

  const size_t MB = 1024 * 1024;
  const size_t XS_OFF = 32 * 1024;
  const size_t H_OFF  = XS_OFF + 8 * MB;
  const size_t W0_OFF = H_OFF + 16 * MB;
  const size_t W1_OFF = W0_OFF + 32 * MB;
  const size_t WO_OFF = W1_OFF + 32 * MB;
  const size_t NEED   = WO_OFF + 32 * MB;   // ~120.03 MB

  route_kernel<<<1, 512, 0, stream>>>(ids, sorted_flat, tile_meta);
  zero_kernel<<<(out_size / 4 + 255) / 256, 256, 0, stream>>>((float4*)out,
                                                              out_size / 4);
  if (ws_size >= NEED) {
    unsigned short* xs  = (unsigned short*)((char*)d_ws + XS_OFF);
    unsigned short* h   = (unsigned short*)((char*)d_ws + H_OFF);
    unsigned short* w0T = (unsigned short*)((char*)d_ws + W0_OFF);
    unsigned short* w1T = (unsigned short*)((char*)d_ws + W1_OFF);
    unsigned short* woT = (unsigned short*)((char*)d_ws + WO_OFF);

    convT_kernel<<<dim3(32, 16, 8), 256, 0, stream>>>(wi0, w0T, D_DIM, F_DIM);
    convT_kernel<<<dim3(32, 16, 8), 256, 0, stream>>>(wi1, w1T, D_DIM, F_DIM);
    convT_kernel<<<dim3(16, 32, 8), 256, 0, stream>>>(wo, woT, F_DIM, D_DIM);
    gather_kernel<<<ROWS, 256, 0, stream>>>(x, sorted_flat, xs);

    dim3 g1(MAXTILE, F_DIM / 128);
    gemm1_kernel<<<g1, 256, 0, stream>>>(xs, w0T, w1T, tile_meta, h);
    dim3 g2(MAXTILE, D_DIM / 128);
    gemm2_kernel<<<g2, 256, 0, stream>>>(h, woT, tw, sorted_flat, tile_meta, out);
  } else {
    unsigned short* h = (unsigned short*)((char*)d_ws + 32768);
    dim3 g1(MAXTILE, F_DIM / 128);
    gemm1_fb<<<g1, 256, 0, stream>>>(x, wi0, wi1, sorted_flat, tile_meta, h);
    dim3 g2(MAXTILE, D_DIM / 128);
    gemm2_fb<<<g2, 256, 0, stream>>>(h, wo, tw, sorted_flat, tile_meta, out);
  }
}